// Round 2
// baseline (913.185 us; speedup 1.0000x reference)
//
#include <hip/hip_runtime.h>
#include <hip/hip_bf16.h>

// GCN actor-critic: 3x (segment_sum(h[src], dst) -> Linear+ReLU), then heads.
// CSR build via block-private counting sort (deterministic, coalesced):
//   bhist -> scan(tbl) -> bucket_scatter (packed pairs) -> fine_scatter
// fine_scatter also emits row_ptr (per-node offsets) as a byproduct.

#define HID 128
#define NBLK 256   // edge-partition blocks
#define BSH 6      // 64 nodes per coarse bucket

// ---- 1. coarse histogram: tbl[b*NBLK + k] = #edges of block k in bucket b
__global__ __launch_bounds__(256) void bhist_kernel(const int* __restrict__ dst,
        int* __restrict__ tbl, int ne, int nb, int epb) {
    __shared__ int lcnt[1024];
    const int k = blockIdx.x, t = threadIdx.x;
    for (int b = t; b < nb; b += 256) lcnt[b] = 0;
    __syncthreads();
    const int beg = k * epb, end = min(ne, beg + epb);
    for (int j = beg + t; j < end; j += 256)
        atomicAdd(&lcnt[dst[j] >> BSH], 1);
    __syncthreads();
    for (int b = t; b < nb; b += 256) tbl[b * NBLK + k] = lcnt[b];
}

// ---- 2. exclusive scan of tbl[0..sz) in place (single block, serial chunks)
__global__ __launch_bounds__(1024) void scan_tbl_kernel(int* __restrict__ tbl, int sz) {
    __shared__ int sh[1024];
    const int t = threadIdx.x;
    const int L = (sz + 1023) / 1024;
    const int beg = t * L, end = min(sz, beg + L);
    int s = 0;
    for (int i = beg; i < end; ++i) s += tbl[i];
    sh[t] = s;
    __syncthreads();
    for (int off = 1; off < 1024; off <<= 1) {
        int v = sh[t];
        int a = (t >= off) ? sh[t - off] : 0;
        __syncthreads();
        sh[t] = v + a;
        __syncthreads();
    }
    int prefix = (t == 0) ? 0 : sh[t - 1];
    for (int i = beg; i < end; ++i) { int v = tbl[i]; tbl[i] = prefix; prefix += v; }
}

// ---- 3. scatter edges into block-private per-bucket subranges (packed)
__global__ __launch_bounds__(256) void bucket_scatter_kernel(
        const int* __restrict__ src, const int* __restrict__ dst,
        const int* __restrict__ tbl, int* __restrict__ pairs,
        int ne, int nb, int epb) {
    __shared__ int cur[1024];
    const int k = blockIdx.x, t = threadIdx.x;
    for (int b = t; b < nb; b += 256) cur[b] = tbl[b * NBLK + k];
    __syncthreads();
    const int beg = k * epb, end = min(ne, beg + epb);
    for (int j = beg + t; j < end; j += 256) {
        int d = dst[j];
        int pos = atomicAdd(&cur[d >> BSH], 1);
        pairs[pos] = (src[j] << BSH) | (d & 63);
    }
}

// ---- 4. per-bucket fine scatter; also writes row_ptr
__global__ __launch_bounds__(256) void fine_scatter_kernel(
        const int* __restrict__ pairs, const int* __restrict__ tbl,
        int* __restrict__ row_ptr, int* __restrict__ eidx,
        int ne, int nb, int n) {
    __shared__ int cnt[64], cur[64];
    const int b = blockIdx.x, t = threadIdx.x;
    const int node0 = b << BSH;
    if (t < 64) cnt[t] = 0;
    __syncthreads();
    const int beg = tbl[b * NBLK];
    const int end = (b == nb - 1) ? ne : tbl[(b + 1) * NBLK];
    for (int j = beg + t; j < end; j += 256) atomicAdd(&cnt[pairs[j] & 63], 1);
    __syncthreads();
    if (t == 0) {
        int run = beg;
        #pragma unroll
        for (int i = 0; i < 64; ++i) { cur[i] = run; run += cnt[i]; }
    }
    __syncthreads();
    if (t < 64 && node0 + t < n) row_ptr[node0 + t] = cur[t];
    if (b == nb - 1 && t == 0) row_ptr[n] = ne;
    __syncthreads();
    for (int j = beg + t; j < end; j += 256) {
        int v = pairs[j];
        int pos = atomicAdd(&cur[v & 63], 1);
        eidx[pos] = v >> BSH;
    }
}

// ------------------------------------------------------------- aggregation
// one 32-lane group per node; each lane owns one float4 (4 of 128 dims)
__global__ __launch_bounds__(256) void aggregate_kernel(
        const float4* __restrict__ x, const int* __restrict__ row_ptr,
        const int* __restrict__ eidx, float4* __restrict__ agg, int n) {
    int g = (int)((blockIdx.x * blockDim.x + threadIdx.x) >> 5);
    int lane = threadIdx.x & 31;
    if (g >= n) return;
    const int beg = row_ptr[g], end = row_ptr[g + 1];
    float4 acc = make_float4(0.f, 0.f, 0.f, 0.f);
    int e = beg;
    for (; e + 4 <= end; e += 4) {
        int s0 = eidx[e], s1 = eidx[e + 1], s2 = eidx[e + 2], s3 = eidx[e + 3];
        float4 v0 = x[(size_t)s0 * 32 + lane];
        float4 v1 = x[(size_t)s1 * 32 + lane];
        float4 v2 = x[(size_t)s2 * 32 + lane];
        float4 v3 = x[(size_t)s3 * 32 + lane];
        acc.x += v0.x; acc.y += v0.y; acc.z += v0.z; acc.w += v0.w;
        acc.x += v1.x; acc.y += v1.y; acc.z += v1.z; acc.w += v1.w;
        acc.x += v2.x; acc.y += v2.y; acc.z += v2.z; acc.w += v2.w;
        acc.x += v3.x; acc.y += v3.y; acc.z += v3.z; acc.w += v3.w;
    }
    for (; e < end; ++e) {
        int s = eidx[e];
        float4 v = x[(size_t)s * 32 + lane];
        acc.x += v.x; acc.y += v.y; acc.z += v.z; acc.w += v.w;
    }
    agg[(size_t)g * 32 + lane] = acc;
}

// ---------------------------------------------------------------- GEMM f32
__global__ __launch_bounds__(256) void gemm_relu_kernel(
        const float* __restrict__ A, const float* __restrict__ W,
        const float* __restrict__ bias, float* __restrict__ out, int M) {
    __shared__ float Ash[64][132];
    __shared__ float Wsh[128][64];
    const int row0 = blockIdx.x * 64;
    const int nh = blockIdx.y * 64;
    const int t = threadIdx.x;

    #pragma unroll
    for (int j = 0; j < 8; ++j) {
        int idx = t + 256 * j;
        int r = idx >> 5, c4 = idx & 31;
        float4 v = make_float4(0.f, 0.f, 0.f, 0.f);
        if (row0 + r < M) v = ((const float4*)A)[(size_t)(row0 + r) * 32 + c4];
        *(float4*)&Ash[r][c4 * 4] = v;
    }
    #pragma unroll
    for (int j = 0; j < 8; ++j) {
        int idx = t + 256 * j;
        int r = idx >> 4, c4 = idx & 15;
        float4 v = ((const float4*)W)[(size_t)r * 32 + (nh >> 2) + c4];
        *(float4*)&Wsh[r][c4 * 4] = v;
    }
    __syncthreads();

    const int cg = t & 15, rg = t >> 4;
    const int c0 = cg * 4, r0 = rg * 4;
    float acc[4][4] = {};
    #pragma unroll 4
    for (int k = 0; k < 128; ++k) {
        float4 wv = *(const float4*)&Wsh[k][c0];
        float a0 = Ash[r0 + 0][k];
        float a1 = Ash[r0 + 1][k];
        float a2 = Ash[r0 + 2][k];
        float a3 = Ash[r0 + 3][k];
        acc[0][0] += a0 * wv.x; acc[0][1] += a0 * wv.y; acc[0][2] += a0 * wv.z; acc[0][3] += a0 * wv.w;
        acc[1][0] += a1 * wv.x; acc[1][1] += a1 * wv.y; acc[1][2] += a1 * wv.z; acc[1][3] += a1 * wv.w;
        acc[2][0] += a2 * wv.x; acc[2][1] += a2 * wv.y; acc[2][2] += a2 * wv.z; acc[2][3] += a2 * wv.w;
        acc[3][0] += a3 * wv.x; acc[3][1] += a3 * wv.y; acc[3][2] += a3 * wv.z; acc[3][3] += a3 * wv.w;
    }

    float4 bv = *(const float4*)&bias[nh + c0];
    #pragma unroll
    for (int i = 0; i < 4; ++i) {
        int r = row0 + r0 + i;
        if (r < M) {
            float4 o;
            o.x = fmaxf(acc[i][0] + bv.x, 0.f);
            o.y = fmaxf(acc[i][1] + bv.y, 0.f);
            o.z = fmaxf(acc[i][2] + bv.z, 0.f);
            o.w = fmaxf(acc[i][3] + bv.w, 0.f);
            ((float4*)out)[(size_t)r * 32 + ((nh + c0) >> 2)] = o;
        }
    }
}

// ---------------------------------------------------------------- heads
__global__ __launch_bounds__(128) void colsum_part_kernel(
        const float* __restrict__ h, float* __restrict__ part, int n) {
    int d = threadIdx.x;
    float acc = 0.f;
    for (int r = blockIdx.x; r < n; r += gridDim.x)
        acc += h[(size_t)r * 128 + d];
    part[blockIdx.x * 128 + d] = acc;
}

__global__ __launch_bounds__(128) void head_final_kernel(
        const float* __restrict__ part, int nparts,
        const float* __restrict__ w_v, const float* __restrict__ b_v,
        const float* __restrict__ w_pd, const float* __restrict__ b_pd,
        float* __restrict__ out, int n_nodes) {
    __shared__ float sv[128], sd[128];
    int d = threadIdx.x;
    float s = 0.f;
    for (int i = 0; i < nparts; ++i) s += part[i * 128 + d];
    float m = s / (float)n_nodes;
    sv[d] = m * w_v[d];
    sd[d] = m * w_pd[d];
    __syncthreads();
    for (int off = 64; off > 0; off >>= 1) {
        if (d < off) { sv[d] += sv[d + off]; sd[d] += sd[d + off]; }
        __syncthreads();
    }
    if (d == 0) {
        out[n_nodes] = sd[0] + b_pd[0];
        out[n_nodes + 1] = sv[0] + b_v[0];
    }
}

__global__ __launch_bounds__(256) void pig_kernel(
        const float* __restrict__ h, const float* __restrict__ w_pg,
        const float* __restrict__ b_pg, float* __restrict__ out, int n) {
    int g = (int)((blockIdx.x * blockDim.x + threadIdx.x) >> 6);
    int l = threadIdx.x & 63;
    if (g >= n) return;
    float acc = h[(size_t)g * 128 + l] * w_pg[l] +
                h[(size_t)g * 128 + 64 + l] * w_pg[64 + l];
    #pragma unroll
    for (int off = 32; off > 0; off >>= 1) acc += __shfl_xor(acc, off);
    if (l == 0) out[g] = acc + b_pg[0];
}

// ---------------------------------------------------------------- launcher
static inline size_t align_up(size_t v, size_t a) { return (v + a - 1) & ~(a - 1); }

extern "C" void kernel_launch(void* const* d_in, const int* in_sizes, int n_in,
                              void* d_out, int out_size, void* d_ws, size_t ws_size,
                              hipStream_t stream) {
    const float* x    = (const float*)d_in[0];
    const int*   src  = (const int*)d_in[1];
    const int*   dst  = (const int*)d_in[2];
    const float* W0   = (const float*)d_in[3];
    const float* b0   = (const float*)d_in[4];
    const float* W1   = (const float*)d_in[5];
    const float* b1   = (const float*)d_in[6];
    const float* W2   = (const float*)d_in[7];
    const float* b2   = (const float*)d_in[8];
    const float* w_pg = (const float*)d_in[9];
    const float* b_pg = (const float*)d_in[10];
    const float* w_pd = (const float*)d_in[11];
    const float* b_pd = (const float*)d_in[12];
    const float* w_v  = (const float*)d_in[13];
    const float* b_v  = (const float*)d_in[14];
    float* out = (float*)d_out;

    const int NN = in_sizes[0] / HID;          // 50000
    const int NE = in_sizes[1];                // 1600000
    const int NB = (NN + 63) >> BSH;           // coarse buckets (<=1024)
    const int SZ = NB * NBLK;                  // histogram table size
    const int EPB = (NE + NBLK - 1) / NBLK;    // edges per partition block

    // workspace carve-up
    char* w = (char*)d_ws;
    int* tbl     = (int*)w;   w += align_up((size_t)SZ * 4, 256);
    int* row_ptr = (int*)w;   w += align_up((size_t)(NN + 1) * 4, 256);
    int* eidx    = (int*)w;   w += align_up((size_t)NE * 4, 256);
    float* agg   = (float*)w; w += align_up((size_t)NN * HID * 4, 256);
    float* h     = (float*)w; w += align_up((size_t)NN * HID * 4, 256);
    float* part  = (float*)w; w += align_up((size_t)128 * 128 * 4, 256);
    int* pairs   = (int*)agg;  // alias: pairs dead before agg is written
    (void)ws_size; (void)n_in; (void)out_size;

    // ---- build CSR by dst (reused for all 3 layers)
    bhist_kernel<<<NBLK, 256, 0, stream>>>(dst, tbl, NE, NB, EPB);
    scan_tbl_kernel<<<1, 1024, 0, stream>>>(tbl, SZ);
    bucket_scatter_kernel<<<NBLK, 256, 0, stream>>>(src, dst, tbl, pairs, NE, NB, EPB);
    fine_scatter_kernel<<<NB, 256, 0, stream>>>(pairs, tbl, row_ptr, eidx, NE, NB, NN);

    const int agg_blocks = (NN * 32 + 255) / 256;
    dim3 gemm_grid((NN + 63) / 64, 2);

    aggregate_kernel<<<agg_blocks, 256, 0, stream>>>((const float4*)x, row_ptr, eidx,
                                                     (float4*)agg, NN);
    gemm_relu_kernel<<<gemm_grid, 256, 0, stream>>>(agg, W0, b0, h, NN);

    aggregate_kernel<<<agg_blocks, 256, 0, stream>>>((const float4*)h, row_ptr, eidx,
                                                     (float4*)agg, NN);
    gemm_relu_kernel<<<gemm_grid, 256, 0, stream>>>(agg, W1, b1, h, NN);

    aggregate_kernel<<<agg_blocks, 256, 0, stream>>>((const float4*)h, row_ptr, eidx,
                                                     (float4*)agg, NN);
    gemm_relu_kernel<<<gemm_grid, 256, 0, stream>>>(agg, W2, b2, h, NN);

    // ---- heads
    colsum_part_kernel<<<128, 128, 0, stream>>>(h, part, NN);
    head_final_kernel<<<1, 128, 0, stream>>>(part, 128, w_v, b_v, w_pd, b_pd, out, NN);
    pig_kernel<<<(NN * 64 + 255) / 256, 256, 0, stream>>>(h, w_pg, b_pg, out, NN);
}

// Round 3
// 602.743 us; speedup vs baseline: 1.5150x; 1.5150x over previous
//
#include <hip/hip_runtime.h>
#include <hip/hip_bf16.h>

// GCN actor-critic: 3x (segment_sum(h[src], dst) -> Linear+ReLU), then heads.
// CSR build via block-private counting sort (deterministic layout, coalesced):
//   bhist -> hierarchical scan(tbl) -> bucket_scatter (packed) -> fine_scatter
// fine_scatter also emits row_ptr (per-node offsets) as a byproduct.

#define HID 128
#define NBLK 256       // edge-partition blocks
#define BSH 6          // 64 nodes per coarse bucket
#define SCAN_CHUNK 1024

// ---- 1. coarse histogram: tbl[b*NBLK + k] = #edges of block k in bucket b
__global__ __launch_bounds__(256) void bhist_kernel(const int* __restrict__ dst,
        int* __restrict__ tbl, int ne, int nb, int epb) {
    __shared__ int lcnt[1024];
    const int k = blockIdx.x, t = threadIdx.x;
    for (int b = t; b < nb; b += 256) lcnt[b] = 0;
    __syncthreads();
    const int beg = k * epb, end = min(ne, beg + epb);
    for (int j = beg + t; j < end; j += 256)
        atomicAdd(&lcnt[dst[j] >> BSH], 1);
    __syncthreads();
    for (int b = t; b < nb; b += 256) tbl[b * NBLK + k] = lcnt[b];
}

// ---- 2. hierarchical exclusive scan of tbl[0..sz) (3 passes, multi-block)
__global__ __launch_bounds__(256) void scan_p1_kernel(const int* __restrict__ tbl,
        int* __restrict__ bsum, int sz) {
    __shared__ int sh[256];
    const int g = blockIdx.x, t = threadIdx.x;
    const int base = g * SCAN_CHUNK + t * 4;
    int s = 0;
    if (base + 3 < sz) {
        int4 v = *(const int4*)(tbl + base);
        s = v.x + v.y + v.z + v.w;
    } else {
        for (int i = 0; i < 4; ++i) if (base + i < sz) s += tbl[base + i];
    }
    sh[t] = s;
    __syncthreads();
    for (int off = 128; off > 0; off >>= 1) {
        if (t < off) sh[t] += sh[t + off];
        __syncthreads();
    }
    if (t == 0) bsum[g] = sh[0];
}

__global__ __launch_bounds__(256) void scan_p2_kernel(int* __restrict__ bsum, int ng) {
    __shared__ int sh[256];
    const int t = threadIdx.x;
    int v = (t < ng) ? bsum[t] : 0;
    sh[t] = v;
    __syncthreads();
    for (int off = 1; off < 256; off <<= 1) {
        int a = sh[t];
        int b = (t >= off) ? sh[t - off] : 0;
        __syncthreads();
        sh[t] = a + b;
        __syncthreads();
    }
    if (t < ng) bsum[t] = sh[t] - v;   // exclusive
}

__global__ __launch_bounds__(256) void scan_p3_kernel(int* __restrict__ tbl,
        const int* __restrict__ bsum, int sz) {
    __shared__ int sh[256];
    const int g = blockIdx.x, t = threadIdx.x;
    const int base = g * SCAN_CHUNK + t * 4;
    int4 v = make_int4(0, 0, 0, 0);
    if (base + 3 < sz) {
        v = *(const int4*)(tbl + base);
    } else {
        if (base + 0 < sz) v.x = tbl[base + 0];
        if (base + 1 < sz) v.y = tbl[base + 1];
        if (base + 2 < sz) v.z = tbl[base + 2];
    }
    int s = v.x + v.y + v.z + v.w;
    sh[t] = s;
    __syncthreads();
    for (int off = 1; off < 256; off <<= 1) {
        int a = sh[t];
        int b = (t >= off) ? sh[t - off] : 0;
        __syncthreads();
        sh[t] = a + b;
        __syncthreads();
    }
    int pre = bsum[g] + sh[t] - s;     // exclusive prefix of this thread's 4
    int o0 = pre, o1 = pre + v.x, o2 = o1 + v.y, o3 = o2 + v.z;
    if (base + 3 < sz) {
        *(int4*)(tbl + base) = make_int4(o0, o1, o2, o3);
    } else {
        if (base + 0 < sz) tbl[base + 0] = o0;
        if (base + 1 < sz) tbl[base + 1] = o1;
        if (base + 2 < sz) tbl[base + 2] = o2;
    }
}

// ---- 3. scatter edges into block-private per-bucket subranges (packed)
__global__ __launch_bounds__(256) void bucket_scatter_kernel(
        const int* __restrict__ src, const int* __restrict__ dst,
        const int* __restrict__ tbl, int* __restrict__ pairs,
        int ne, int nb, int epb) {
    __shared__ int cur[1024];
    const int k = blockIdx.x, t = threadIdx.x;
    for (int b = t; b < nb; b += 256) cur[b] = tbl[b * NBLK + k];
    __syncthreads();
    const int beg = k * epb, end = min(ne, beg + epb);
    for (int j = beg + t; j < end; j += 256) {
        int d = dst[j];
        int pos = atomicAdd(&cur[d >> BSH], 1);
        pairs[pos] = (src[j] << BSH) | (d & 63);
    }
}

// ---- 4. per-bucket fine scatter; also writes row_ptr
__global__ __launch_bounds__(256) void fine_scatter_kernel(
        const int* __restrict__ pairs, const int* __restrict__ tbl,
        int* __restrict__ row_ptr, int* __restrict__ eidx,
        int ne, int nb, int n) {
    __shared__ int cnt[64], cur[64];
    const int b = blockIdx.x, t = threadIdx.x;
    const int node0 = b << BSH;
    if (t < 64) cnt[t] = 0;
    __syncthreads();
    const int beg = tbl[b * NBLK];
    const int end = (b == nb - 1) ? ne : tbl[(b + 1) * NBLK];
    for (int j = beg + t; j < end; j += 256) atomicAdd(&cnt[pairs[j] & 63], 1);
    __syncthreads();
    if (t == 0) {
        int run = beg;
        #pragma unroll
        for (int i = 0; i < 64; ++i) { cur[i] = run; run += cnt[i]; }
    }
    __syncthreads();
    if (t < 64 && node0 + t < n) row_ptr[node0 + t] = cur[t];
    if (b == nb - 1 && t == 0) row_ptr[n] = ne;
    __syncthreads();
    for (int j = beg + t; j < end; j += 256) {
        int v = pairs[j];
        int pos = atomicAdd(&cur[v & 63], 1);
        eidx[pos] = v >> BSH;
    }
}

// ------------------------------------------------------------- aggregation
// one 32-lane group per node; each lane owns one float4 (4 of 128 dims)
__global__ __launch_bounds__(256) void aggregate_kernel(
        const float4* __restrict__ x, const int* __restrict__ row_ptr,
        const int* __restrict__ eidx, float4* __restrict__ agg, int n) {
    int g = (int)((blockIdx.x * blockDim.x + threadIdx.x) >> 5);
    int lane = threadIdx.x & 31;
    if (g >= n) return;
    const int beg = row_ptr[g], end = row_ptr[g + 1];
    float4 acc = make_float4(0.f, 0.f, 0.f, 0.f);
    int e = beg;
    for (; e + 4 <= end; e += 4) {
        int s0 = eidx[e], s1 = eidx[e + 1], s2 = eidx[e + 2], s3 = eidx[e + 3];
        float4 v0 = x[(size_t)s0 * 32 + lane];
        float4 v1 = x[(size_t)s1 * 32 + lane];
        float4 v2 = x[(size_t)s2 * 32 + lane];
        float4 v3 = x[(size_t)s3 * 32 + lane];
        acc.x += v0.x; acc.y += v0.y; acc.z += v0.z; acc.w += v0.w;
        acc.x += v1.x; acc.y += v1.y; acc.z += v1.z; acc.w += v1.w;
        acc.x += v2.x; acc.y += v2.y; acc.z += v2.z; acc.w += v2.w;
        acc.x += v3.x; acc.y += v3.y; acc.z += v3.z; acc.w += v3.w;
    }
    for (; e < end; ++e) {
        int s = eidx[e];
        float4 v = x[(size_t)s * 32 + lane];
        acc.x += v.x; acc.y += v.y; acc.z += v.z; acc.w += v.w;
    }
    agg[(size_t)g * 32 + lane] = acc;
}

// ---------------------------------------------------------------- GEMM f32
__global__ __launch_bounds__(256) void gemm_relu_kernel(
        const float* __restrict__ A, const float* __restrict__ W,
        const float* __restrict__ bias, float* __restrict__ out, int M) {
    __shared__ float Ash[64][132];
    __shared__ float Wsh[128][64];
    const int row0 = blockIdx.x * 64;
    const int nh = blockIdx.y * 64;
    const int t = threadIdx.x;

    #pragma unroll
    for (int j = 0; j < 8; ++j) {
        int idx = t + 256 * j;
        int r = idx >> 5, c4 = idx & 31;
        float4 v = make_float4(0.f, 0.f, 0.f, 0.f);
        if (row0 + r < M) v = ((const float4*)A)[(size_t)(row0 + r) * 32 + c4];
        *(float4*)&Ash[r][c4 * 4] = v;
    }
    #pragma unroll
    for (int j = 0; j < 8; ++j) {
        int idx = t + 256 * j;
        int r = idx >> 4, c4 = idx & 15;
        float4 v = ((const float4*)W)[(size_t)r * 32 + (nh >> 2) + c4];
        *(float4*)&Wsh[r][c4 * 4] = v;
    }
    __syncthreads();

    const int cg = t & 15, rg = t >> 4;
    const int c0 = cg * 4, r0 = rg * 4;
    float acc[4][4] = {};
    #pragma unroll 4
    for (int k = 0; k < 128; ++k) {
        float4 wv = *(const float4*)&Wsh[k][c0];
        float a0 = Ash[r0 + 0][k];
        float a1 = Ash[r0 + 1][k];
        float a2 = Ash[r0 + 2][k];
        float a3 = Ash[r0 + 3][k];
        acc[0][0] += a0 * wv.x; acc[0][1] += a0 * wv.y; acc[0][2] += a0 * wv.z; acc[0][3] += a0 * wv.w;
        acc[1][0] += a1 * wv.x; acc[1][1] += a1 * wv.y; acc[1][2] += a1 * wv.z; acc[1][3] += a1 * wv.w;
        acc[2][0] += a2 * wv.x; acc[2][1] += a2 * wv.y; acc[2][2] += a2 * wv.z; acc[2][3] += a2 * wv.w;
        acc[3][0] += a3 * wv.x; acc[3][1] += a3 * wv.y; acc[3][2] += a3 * wv.z; acc[3][3] += a3 * wv.w;
    }

    float4 bv = *(const float4*)&bias[nh + c0];
    #pragma unroll
    for (int i = 0; i < 4; ++i) {
        int r = row0 + r0 + i;
        if (r < M) {
            float4 o;
            o.x = fmaxf(acc[i][0] + bv.x, 0.f);
            o.y = fmaxf(acc[i][1] + bv.y, 0.f);
            o.z = fmaxf(acc[i][2] + bv.z, 0.f);
            o.w = fmaxf(acc[i][3] + bv.w, 0.f);
            ((float4*)out)[(size_t)r * 32 + ((nh + c0) >> 2)] = o;
        }
    }
}

// ---------------------------------------------------------------- heads
__global__ __launch_bounds__(128) void colsum_part_kernel(
        const float* __restrict__ h, float* __restrict__ part, int n) {
    int d = threadIdx.x;
    float acc = 0.f;
    for (int r = blockIdx.x; r < n; r += gridDim.x)
        acc += h[(size_t)r * 128 + d];
    part[blockIdx.x * 128 + d] = acc;
}

__global__ __launch_bounds__(128) void head_final_kernel(
        const float* __restrict__ part, int nparts,
        const float* __restrict__ w_v, const float* __restrict__ b_v,
        const float* __restrict__ w_pd, const float* __restrict__ b_pd,
        float* __restrict__ out, int n_nodes) {
    __shared__ float sv[128], sd[128];
    int d = threadIdx.x;
    float s = 0.f;
    for (int i = 0; i < nparts; ++i) s += part[i * 128 + d];
    float m = s / (float)n_nodes;
    sv[d] = m * w_v[d];
    sd[d] = m * w_pd[d];
    __syncthreads();
    for (int off = 64; off > 0; off >>= 1) {
        if (d < off) { sv[d] += sv[d + off]; sd[d] += sd[d + off]; }
        __syncthreads();
    }
    if (d == 0) {
        out[n_nodes] = sd[0] + b_pd[0];
        out[n_nodes + 1] = sv[0] + b_v[0];
    }
}

__global__ __launch_bounds__(256) void pig_kernel(
        const float* __restrict__ h, const float* __restrict__ w_pg,
        const float* __restrict__ b_pg, float* __restrict__ out, int n) {
    int g = (int)((blockIdx.x * blockDim.x + threadIdx.x) >> 6);
    int l = threadIdx.x & 63;
    if (g >= n) return;
    float acc = h[(size_t)g * 128 + l] * w_pg[l] +
                h[(size_t)g * 128 + 64 + l] * w_pg[64 + l];
    #pragma unroll
    for (int off = 32; off > 0; off >>= 1) acc += __shfl_xor(acc, off);
    if (l == 0) out[g] = acc + b_pg[0];
}

// ---------------------------------------------------------------- launcher
static inline size_t align_up(size_t v, size_t a) { return (v + a - 1) & ~(a - 1); }

extern "C" void kernel_launch(void* const* d_in, const int* in_sizes, int n_in,
                              void* d_out, int out_size, void* d_ws, size_t ws_size,
                              hipStream_t stream) {
    const float* x    = (const float*)d_in[0];
    const int*   src  = (const int*)d_in[1];
    const int*   dst  = (const int*)d_in[2];
    const float* W0   = (const float*)d_in[3];
    const float* b0   = (const float*)d_in[4];
    const float* W1   = (const float*)d_in[5];
    const float* b1   = (const float*)d_in[6];
    const float* W2   = (const float*)d_in[7];
    const float* b2   = (const float*)d_in[8];
    const float* w_pg = (const float*)d_in[9];
    const float* b_pg = (const float*)d_in[10];
    const float* w_pd = (const float*)d_in[11];
    const float* b_pd = (const float*)d_in[12];
    const float* w_v  = (const float*)d_in[13];
    const float* b_v  = (const float*)d_in[14];
    float* out = (float*)d_out;

    const int NN = in_sizes[0] / HID;          // 50000
    const int NE = in_sizes[1];                // 1600000
    const int NB = (NN + 63) >> BSH;           // coarse buckets
    const int SZ = NB * NBLK;                  // histogram table size (~200K)
    const int EPB = (NE + NBLK - 1) / NBLK;    // edges per partition block
    const int NG = (SZ + SCAN_CHUNK - 1) / SCAN_CHUNK;  // scan chunks (<=256)

    // workspace carve-up
    char* w = (char*)d_ws;
    int* tbl     = (int*)w;   w += align_up((size_t)SZ * 4, 256);
    int* bsum    = (int*)w;   w += align_up((size_t)256 * 4, 256);
    int* row_ptr = (int*)w;   w += align_up((size_t)(NN + 1) * 4, 256);
    int* eidx    = (int*)w;   w += align_up((size_t)NE * 4, 256);
    float* agg   = (float*)w; w += align_up((size_t)NN * HID * 4, 256);
    float* h     = (float*)w; w += align_up((size_t)NN * HID * 4, 256);
    float* part  = (float*)w; w += align_up((size_t)128 * 128 * 4, 256);
    int* pairs   = (int*)agg;  // alias: pairs dead before agg is written
    (void)ws_size; (void)n_in; (void)out_size;

    // ---- build CSR by dst (reused for all 3 layers)
    bhist_kernel<<<NBLK, 256, 0, stream>>>(dst, tbl, NE, NB, EPB);
    scan_p1_kernel<<<NG, 256, 0, stream>>>(tbl, bsum, SZ);
    scan_p2_kernel<<<1, 256, 0, stream>>>(bsum, NG);
    scan_p3_kernel<<<NG, 256, 0, stream>>>(tbl, bsum, SZ);
    bucket_scatter_kernel<<<NBLK, 256, 0, stream>>>(src, dst, tbl, pairs, NE, NB, EPB);
    fine_scatter_kernel<<<NB, 256, 0, stream>>>(pairs, tbl, row_ptr, eidx, NE, NB, NN);

    const int agg_blocks = (NN * 32 + 255) / 256;
    dim3 gemm_grid((NN + 63) / 64, 2);

    aggregate_kernel<<<agg_blocks, 256, 0, stream>>>((const float4*)x, row_ptr, eidx,
                                                     (float4*)agg, NN);
    gemm_relu_kernel<<<gemm_grid, 256, 0, stream>>>(agg, W0, b0, h, NN);

    aggregate_kernel<<<agg_blocks, 256, 0, stream>>>((const float4*)h, row_ptr, eidx,
                                                     (float4*)agg, NN);
    gemm_relu_kernel<<<gemm_grid, 256, 0, stream>>>(agg, W1, b1, h, NN);

    aggregate_kernel<<<agg_blocks, 256, 0, stream>>>((const float4*)h, row_ptr, eidx,
                                                     (float4*)agg, NN);
    gemm_relu_kernel<<<gemm_grid, 256, 0, stream>>>(agg, W2, b2, h, NN);

    // ---- heads
    colsum_part_kernel<<<128, 128, 0, stream>>>(h, part, NN);
    head_final_kernel<<<1, 128, 0, stream>>>(part, 128, w_v, b_v, w_pd, b_pd, out, NN);
    pig_kernel<<<(NN * 64 + 255) / 256, 256, 0, stream>>>(h, w_pg, b_pg, out, NN);
}

// Round 4
// 404.339 us; speedup vs baseline: 2.2585x; 1.4907x over previous
//
#include <hip/hip_runtime.h>
#include <hip/hip_bf16.h>

// GCN actor-critic, bf16 feature pipeline:
//   CSR build (counting sort) -> 3x [bf16 gather-sum -> MFMA bf16 GEMM+ReLU]
//   -> heads. All accumulation in f32; features stored bf16 (RNE).

#define HID 128
#define NBLK 256       // edge-partition blocks
#define BSH 6          // 64 nodes per coarse bucket
#define SCAN_CHUNK 1024

typedef __attribute__((ext_vector_type(8))) short short8;
typedef __attribute__((ext_vector_type(4))) float f32x4;

__device__ __forceinline__ unsigned short f2bf(float f) {
    unsigned int u = __float_as_uint(f);
    unsigned int r = (u + 0x7fffu + ((u >> 16) & 1u)) >> 16;   // RNE
    return (unsigned short)r;
}
__device__ __forceinline__ float bf2f(unsigned short u) {
    return __uint_as_float(((unsigned int)u) << 16);
}

// ---------------------------------------------------------------- converts
__global__ __launch_bounds__(256) void f32_to_bf16_kernel(
        const float4* __restrict__ in, ushort4* __restrict__ out, int n4) {
    for (int i = blockIdx.x * blockDim.x + threadIdx.x; i < n4; i += gridDim.x * blockDim.x) {
        float4 v = in[i];
        ushort4 o;
        o.x = f2bf(v.x); o.y = f2bf(v.y); o.z = f2bf(v.z); o.w = f2bf(v.w);
        out[i] = o;
    }
}

// pack W[128][128] f32 into B-fragment order: packw[((c*4+kk)*64+lane)*8+i] =
// bf16(W[kk*32 + (lane>>4)*8 + i][c*16 + (lane&15)])
__global__ __launch_bounds__(256) void pack_w_kernel(
        const float* __restrict__ W, unsigned short* __restrict__ packw) {
    for (int j = blockIdx.x * blockDim.x + threadIdx.x; j < 16384; j += gridDim.x * blockDim.x) {
        int i = j & 7, lane = (j >> 3) & 63, kk = (j >> 9) & 3, c = (j >> 11) & 7;
        int k = kk * 32 + (lane >> 4) * 8 + i;
        int col = c * 16 + (lane & 15);
        packw[j] = f2bf(W[k * 128 + col]);
    }
}

// ---- 1. coarse histogram: tbl[b*NBLK + k] = #edges of block k in bucket b
__global__ __launch_bounds__(256) void bhist_kernel(const int* __restrict__ dst,
        int* __restrict__ tbl, int ne, int nb, int epb) {
    __shared__ int lcnt[1024];
    const int k = blockIdx.x, t = threadIdx.x;
    for (int b = t; b < nb; b += 256) lcnt[b] = 0;
    __syncthreads();
    const int beg = k * epb, end = min(ne, beg + epb);
    for (int j = beg + t; j < end; j += 256)
        atomicAdd(&lcnt[dst[j] >> BSH], 1);
    __syncthreads();
    for (int b = t; b < nb; b += 256) tbl[b * NBLK + k] = lcnt[b];
}

// ---- 2. hierarchical exclusive scan of tbl[0..sz)
__global__ __launch_bounds__(256) void scan_p1_kernel(const int* __restrict__ tbl,
        int* __restrict__ bsum, int sz) {
    __shared__ int sh[256];
    const int g = blockIdx.x, t = threadIdx.x;
    const int base = g * SCAN_CHUNK + t * 4;
    int s = 0;
    if (base + 3 < sz) {
        int4 v = *(const int4*)(tbl + base);
        s = v.x + v.y + v.z + v.w;
    } else {
        for (int i = 0; i < 4; ++i) if (base + i < sz) s += tbl[base + i];
    }
    sh[t] = s;
    __syncthreads();
    for (int off = 128; off > 0; off >>= 1) {
        if (t < off) sh[t] += sh[t + off];
        __syncthreads();
    }
    if (t == 0) bsum[g] = sh[0];
}

__global__ __launch_bounds__(256) void scan_p2_kernel(int* __restrict__ bsum, int ng) {
    __shared__ int sh[256];
    const int t = threadIdx.x;
    int v = (t < ng) ? bsum[t] : 0;
    sh[t] = v;
    __syncthreads();
    for (int off = 1; off < 256; off <<= 1) {
        int a = sh[t];
        int b = (t >= off) ? sh[t - off] : 0;
        __syncthreads();
        sh[t] = a + b;
        __syncthreads();
    }
    if (t < ng) bsum[t] = sh[t] - v;   // exclusive
}

__global__ __launch_bounds__(256) void scan_p3_kernel(int* __restrict__ tbl,
        const int* __restrict__ bsum, int sz) {
    __shared__ int sh[256];
    const int g = blockIdx.x, t = threadIdx.x;
    const int base = g * SCAN_CHUNK + t * 4;
    int4 v = make_int4(0, 0, 0, 0);
    if (base + 3 < sz) {
        v = *(const int4*)(tbl + base);
    } else {
        if (base + 0 < sz) v.x = tbl[base + 0];
        if (base + 1 < sz) v.y = tbl[base + 1];
        if (base + 2 < sz) v.z = tbl[base + 2];
    }
    int s = v.x + v.y + v.z + v.w;
    sh[t] = s;
    __syncthreads();
    for (int off = 1; off < 256; off <<= 1) {
        int a = sh[t];
        int b = (t >= off) ? sh[t - off] : 0;
        __syncthreads();
        sh[t] = a + b;
        __syncthreads();
    }
    int pre = bsum[g] + sh[t] - s;
    int o0 = pre, o1 = pre + v.x, o2 = o1 + v.y, o3 = o2 + v.z;
    if (base + 3 < sz) {
        *(int4*)(tbl + base) = make_int4(o0, o1, o2, o3);
    } else {
        if (base + 0 < sz) tbl[base + 0] = o0;
        if (base + 1 < sz) tbl[base + 1] = o1;
        if (base + 2 < sz) tbl[base + 2] = o2;
    }
}

// ---- 3. scatter edges into block-private per-bucket subranges (packed)
__global__ __launch_bounds__(256) void bucket_scatter_kernel(
        const int* __restrict__ src, const int* __restrict__ dst,
        const int* __restrict__ tbl, int* __restrict__ pairs,
        int ne, int nb, int epb) {
    __shared__ int cur[1024];
    const int k = blockIdx.x, t = threadIdx.x;
    for (int b = t; b < nb; b += 256) cur[b] = tbl[b * NBLK + k];
    __syncthreads();
    const int beg = k * epb, end = min(ne, beg + epb);
    for (int j = beg + t; j < end; j += 256) {
        int d = dst[j];
        int pos = atomicAdd(&cur[d >> BSH], 1);
        pairs[pos] = (src[j] << BSH) | (d & 63);
    }
}

// ---- 4. per-bucket fine scatter; also writes row_ptr
__global__ __launch_bounds__(256) void fine_scatter_kernel(
        const int* __restrict__ pairs, const int* __restrict__ tbl,
        int* __restrict__ row_ptr, int* __restrict__ eidx,
        int ne, int nb, int n) {
    __shared__ int cnt[64], cur[64];
    const int b = blockIdx.x, t = threadIdx.x;
    const int node0 = b << BSH;
    if (t < 64) cnt[t] = 0;
    __syncthreads();
    const int beg = tbl[b * NBLK];
    const int end = (b == nb - 1) ? ne : tbl[(b + 1) * NBLK];
    for (int j = beg + t; j < end; j += 256) atomicAdd(&cnt[pairs[j] & 63], 1);
    __syncthreads();
    if (t == 0) {
        int run = beg;
        #pragma unroll
        for (int i = 0; i < 64; ++i) { cur[i] = run; run += cnt[i]; }
    }
    __syncthreads();
    if (t < 64 && node0 + t < n) row_ptr[node0 + t] = cur[t];
    if (b == nb - 1 && t == 0) row_ptr[n] = ne;
    __syncthreads();
    for (int j = beg + t; j < end; j += 256) {
        int v = pairs[j];
        int pos = atomicAdd(&cur[v & 63], 1);
        eidx[pos] = v >> BSH;
    }
}

// ------------------------------------------------------------- aggregation
// one 32-lane group per node; each lane owns 4 bf16 dims (8B = uint2)
__global__ __launch_bounds__(256) void aggregate_bf_kernel(
        const uint2* __restrict__ xb, const int* __restrict__ row_ptr,
        const int* __restrict__ eidx, uint2* __restrict__ aggb, int n) {
    int g = (int)((blockIdx.x * blockDim.x + threadIdx.x) >> 5);
    int lane = threadIdx.x & 31;
    if (g >= n) return;
    const int beg = row_ptr[g], end = row_ptr[g + 1];
    float4 acc = make_float4(0.f, 0.f, 0.f, 0.f);
    int e = beg;
    for (; e + 4 <= end; e += 4) {
        int s0 = eidx[e], s1 = eidx[e + 1], s2 = eidx[e + 2], s3 = eidx[e + 3];
        uint2 v0 = xb[(size_t)s0 * 32 + lane];
        uint2 v1 = xb[(size_t)s1 * 32 + lane];
        uint2 v2 = xb[(size_t)s2 * 32 + lane];
        uint2 v3 = xb[(size_t)s3 * 32 + lane];
        acc.x += __uint_as_float(v0.x << 16); acc.y += __uint_as_float(v0.x & 0xffff0000u);
        acc.z += __uint_as_float(v0.y << 16); acc.w += __uint_as_float(v0.y & 0xffff0000u);
        acc.x += __uint_as_float(v1.x << 16); acc.y += __uint_as_float(v1.x & 0xffff0000u);
        acc.z += __uint_as_float(v1.y << 16); acc.w += __uint_as_float(v1.y & 0xffff0000u);
        acc.x += __uint_as_float(v2.x << 16); acc.y += __uint_as_float(v2.x & 0xffff0000u);
        acc.z += __uint_as_float(v2.y << 16); acc.w += __uint_as_float(v2.y & 0xffff0000u);
        acc.x += __uint_as_float(v3.x << 16); acc.y += __uint_as_float(v3.x & 0xffff0000u);
        acc.z += __uint_as_float(v3.y << 16); acc.w += __uint_as_float(v3.y & 0xffff0000u);
    }
    for (; e < end; ++e) {
        int s = eidx[e];
        uint2 v = xb[(size_t)s * 32 + lane];
        acc.x += __uint_as_float(v.x << 16); acc.y += __uint_as_float(v.x & 0xffff0000u);
        acc.z += __uint_as_float(v.y << 16); acc.w += __uint_as_float(v.y & 0xffff0000u);
    }
    uint2 o;
    o.x = (unsigned)f2bf(acc.x) | ((unsigned)f2bf(acc.y) << 16);
    o.y = (unsigned)f2bf(acc.z) | ((unsigned)f2bf(acc.w) << 16);
    aggb[(size_t)g * 32 + lane] = o;
}

// ---------------------------------------------------------- GEMM bf16 MFMA
// out[M,128] = relu(A[M,128] @ W + b), A,out bf16, acc f32.
// 4 waves/block; wave w owns rows [blk*64+w*16, +16), all 8 col-tiles.
__global__ __launch_bounds__(256) void gemm_mfma_kernel(
        const short* __restrict__ A, const short* __restrict__ packw,
        const float* __restrict__ bias, unsigned short* __restrict__ out, int M) {
    const int w = threadIdx.x >> 6, l = threadIdx.x & 63;
    const int m = l & 15, hi = l >> 4;
    const int row0 = blockIdx.x * 64 + w * 16;
    const int arow = row0 + m;
    const bool valid = arow < M;

    short8 afrag[4];
    #pragma unroll
    for (int kk = 0; kk < 4; ++kk) {
        if (valid)
            afrag[kk] = *(const short8*)(A + (size_t)arow * 128 + kk * 32 + hi * 8);
        else
            afrag[kk] = short8{0, 0, 0, 0, 0, 0, 0, 0};
    }

    f32x4 acc[8] = {};
    #pragma unroll
    for (int kk = 0; kk < 4; ++kk) {
        #pragma unroll
        for (int c = 0; c < 8; ++c) {
            short8 bfrag = *(const short8*)(packw + ((size_t)(c * 4 + kk) * 64 + l) * 8);
            acc[c] = __builtin_amdgcn_mfma_f32_16x16x32_bf16(afrag[kk], bfrag, acc[c], 0, 0, 0);
        }
    }

    #pragma unroll
    for (int c = 0; c < 8; ++c) {
        float bcol = bias[c * 16 + m];
        #pragma unroll
        for (int r = 0; r < 4; ++r) {
            int row = row0 + hi * 4 + r;
            if (row < M)
                out[(size_t)row * 128 + c * 16 + m] = f2bf(fmaxf(acc[c][r] + bcol, 0.f));
        }
    }
}

// ---------------------------------------------------------------- heads
__global__ __launch_bounds__(128) void colsum_part_kernel(
        const unsigned short* __restrict__ h, float* __restrict__ part, int n) {
    int d = threadIdx.x;
    float acc = 0.f;
    for (int r = blockIdx.x; r < n; r += gridDim.x)
        acc += bf2f(h[(size_t)r * 128 + d]);
    part[blockIdx.x * 128 + d] = acc;
}

__global__ __launch_bounds__(128) void head_final_kernel(
        const float* __restrict__ part, int nparts,
        const float* __restrict__ w_v, const float* __restrict__ b_v,
        const float* __restrict__ w_pd, const float* __restrict__ b_pd,
        float* __restrict__ out, int n_nodes) {
    __shared__ float sv[128], sd[128];
    int d = threadIdx.x;
    float s = 0.f;
    for (int i = 0; i < nparts; ++i) s += part[i * 128 + d];
    float m = s / (float)n_nodes;
    sv[d] = m * w_v[d];
    sd[d] = m * w_pd[d];
    __syncthreads();
    for (int off = 64; off > 0; off >>= 1) {
        if (d < off) { sv[d] += sv[d + off]; sd[d] += sd[d + off]; }
        __syncthreads();
    }
    if (d == 0) {
        out[n_nodes] = sd[0] + b_pd[0];
        out[n_nodes + 1] = sv[0] + b_v[0];
    }
}

__global__ __launch_bounds__(256) void pig_kernel(
        const unsigned short* __restrict__ h, const float* __restrict__ w_pg,
        const float* __restrict__ b_pg, float* __restrict__ out, int n) {
    int g = (int)((blockIdx.x * blockDim.x + threadIdx.x) >> 6);
    int l = threadIdx.x & 63;
    if (g >= n) return;
    float acc = bf2f(h[(size_t)g * 128 + l]) * w_pg[l] +
                bf2f(h[(size_t)g * 128 + 64 + l]) * w_pg[64 + l];
    #pragma unroll
    for (int off = 32; off > 0; off >>= 1) acc += __shfl_xor(acc, off);
    if (l == 0) out[g] = acc + b_pg[0];
}

// ---------------------------------------------------------------- launcher
static inline size_t align_up(size_t v, size_t a) { return (v + a - 1) & ~(a - 1); }

extern "C" void kernel_launch(void* const* d_in, const int* in_sizes, int n_in,
                              void* d_out, int out_size, void* d_ws, size_t ws_size,
                              hipStream_t stream) {
    const float* x    = (const float*)d_in[0];
    const int*   src  = (const int*)d_in[1];
    const int*   dst  = (const int*)d_in[2];
    const float* W0   = (const float*)d_in[3];
    const float* b0   = (const float*)d_in[4];
    const float* W1   = (const float*)d_in[5];
    const float* b1   = (const float*)d_in[6];
    const float* W2   = (const float*)d_in[7];
    const float* b2   = (const float*)d_in[8];
    const float* w_pg = (const float*)d_in[9];
    const float* b_pg = (const float*)d_in[10];
    const float* w_pd = (const float*)d_in[11];
    const float* b_pd = (const float*)d_in[12];
    const float* w_v  = (const float*)d_in[13];
    const float* b_v  = (const float*)d_in[14];
    float* out = (float*)d_out;

    const int NN = in_sizes[0] / HID;          // 50000
    const int NE = in_sizes[1];                // 1600000
    const int NB = (NN + 63) >> BSH;           // coarse buckets
    const int SZ = NB * NBLK;                  // histogram table (~200K ints)
    const int EPB = (NE + NBLK - 1) / NBLK;
    const int NG = (SZ + SCAN_CHUNK - 1) / SCAN_CHUNK;

    // workspace carve-up
    char* w = (char*)d_ws;
    int* tbl      = (int*)w;            w += align_up((size_t)SZ * 4, 256);
    int* bsum     = (int*)w;            w += align_up((size_t)256 * 4, 256);
    int* row_ptr  = (int*)w;            w += align_up((size_t)(NN + 1) * 4, 256);
    int* eidx     = (int*)w;            w += align_up((size_t)NE * 4, 256);
    unsigned short* xb   = (unsigned short*)w; w += align_up((size_t)NN * HID * 2, 256);
    unsigned short* aggb = (unsigned short*)w; w += align_up((size_t)NN * HID * 2, 256);
    unsigned short* hb   = (unsigned short*)w; w += align_up((size_t)NN * HID * 2, 256);
    unsigned short* pw0  = (unsigned short*)w; w += align_up((size_t)16384 * 2, 256);
    unsigned short* pw1  = (unsigned short*)w; w += align_up((size_t)16384 * 2, 256);
    unsigned short* pw2  = (unsigned short*)w; w += align_up((size_t)16384 * 2, 256);
    float* part   = (float*)w;          w += align_up((size_t)128 * 128 * 4, 256);
    int* pairs    = (int*)aggb;  // alias: pairs (6.4MB) dead before aggb written
    (void)ws_size; (void)n_in; (void)out_size;

    // ---- converts (independent of CSR)
    f32_to_bf16_kernel<<<2048, 256, 0, stream>>>((const float4*)x, (ushort4*)xb, NN * 32);
    pack_w_kernel<<<16, 256, 0, stream>>>(W0, pw0);
    pack_w_kernel<<<16, 256, 0, stream>>>(W1, pw1);
    pack_w_kernel<<<16, 256, 0, stream>>>(W2, pw2);

    // ---- build CSR by dst (reused for all 3 layers)
    bhist_kernel<<<NBLK, 256, 0, stream>>>(dst, tbl, NE, NB, EPB);
    scan_p1_kernel<<<NG, 256, 0, stream>>>(tbl, bsum, SZ);
    scan_p2_kernel<<<1, 256, 0, stream>>>(bsum, NG);
    scan_p3_kernel<<<NG, 256, 0, stream>>>(tbl, bsum, SZ);
    bucket_scatter_kernel<<<NBLK, 256, 0, stream>>>(src, dst, tbl, pairs, NE, NB, EPB);
    fine_scatter_kernel<<<NB, 256, 0, stream>>>(pairs, tbl, row_ptr, eidx, NE, NB, NN);

    const int agg_blocks = (NN * 32 + 255) / 256;
    const int gemm_blocks = (NN + 63) / 64;

    aggregate_bf_kernel<<<agg_blocks, 256, 0, stream>>>((const uint2*)xb, row_ptr, eidx,
                                                        (uint2*)aggb, NN);
    gemm_mfma_kernel<<<gemm_blocks, 256, 0, stream>>>((const short*)aggb, (const short*)pw0,
                                                      b0, hb, NN);
    aggregate_bf_kernel<<<agg_blocks, 256, 0, stream>>>((const uint2*)hb, row_ptr, eidx,
                                                        (uint2*)aggb, NN);
    gemm_mfma_kernel<<<gemm_blocks, 256, 0, stream>>>((const short*)aggb, (const short*)pw1,
                                                      b1, hb, NN);
    aggregate_bf_kernel<<<agg_blocks, 256, 0, stream>>>((const uint2*)hb, row_ptr, eidx,
                                                        (uint2*)aggb, NN);
    gemm_mfma_kernel<<<gemm_blocks, 256, 0, stream>>>((const short*)aggb, (const short*)pw2,
                                                      b2, hb, NN);

    // ---- heads
    colsum_part_kernel<<<128, 128, 0, stream>>>(hb, part, NN);
    head_final_kernel<<<1, 128, 0, stream>>>(part, 128, w_v, b_v, w_pd, b_pd, out, NN);
    pig_kernel<<<(NN * 64 + 255) / 256, 256, 0, stream>>>(hb, w_pg, b_pg, out, NN);
}

// Round 5
// 348.560 us; speedup vs baseline: 2.6199x; 1.1600x over previous
//
#include <hip/hip_runtime.h>
#include <hip/hip_bf16.h>

// GCN actor-critic, bf16 feature pipeline:
//   CSR build (counting sort) -> 3x [bf16 gather-sum -> MFMA bf16 GEMM+ReLU]
//   -> heads. All accumulation in f32; features stored bf16 (RNE).

#define HID 128
#define NBLK 256       // edge-partition blocks
#define BSH 6          // 64 nodes per coarse bucket
#define SCAN_CHUNK 1024
#define CS_BLOCKS 256  // colsum partial blocks

typedef __attribute__((ext_vector_type(8))) short short8;
typedef __attribute__((ext_vector_type(4))) float f32x4;

__device__ __forceinline__ unsigned short f2bf(float f) {
    unsigned int u = __float_as_uint(f);
    unsigned int r = (u + 0x7fffu + ((u >> 16) & 1u)) >> 16;   // RNE
    return (unsigned short)r;
}
__device__ __forceinline__ float bf2f(unsigned short u) {
    return __uint_as_float(((unsigned int)u) << 16);
}

// ---------------------------------------------------------------- converts
__global__ __launch_bounds__(256) void f32_to_bf16_kernel(
        const float4* __restrict__ in, ushort4* __restrict__ out, int n4) {
    for (int i = blockIdx.x * blockDim.x + threadIdx.x; i < n4; i += gridDim.x * blockDim.x) {
        float4 v = in[i];
        ushort4 o;
        o.x = f2bf(v.x); o.y = f2bf(v.y); o.z = f2bf(v.z); o.w = f2bf(v.w);
        out[i] = o;
    }
}

// pack W[128][128] f32 into B-fragment order: packw[((c*4+kk)*64+lane)*8+i] =
// bf16(W[kk*32 + (lane>>4)*8 + i][c*16 + (lane&15)])
__global__ __launch_bounds__(256) void pack_w_kernel(
        const float* __restrict__ W, unsigned short* __restrict__ packw) {
    for (int j = blockIdx.x * blockDim.x + threadIdx.x; j < 16384; j += gridDim.x * blockDim.x) {
        int i = j & 7, lane = (j >> 3) & 63, kk = (j >> 9) & 3, c = (j >> 11) & 7;
        int k = kk * 32 + (lane >> 4) * 8 + i;
        int col = c * 16 + (lane & 15);
        packw[j] = f2bf(W[k * 128 + col]);
    }
}

// ---- 1. coarse histogram: tbl[b*NBLK + k] = #edges of block k in bucket b
__global__ __launch_bounds__(256) void bhist_kernel(const int* __restrict__ dst,
        int* __restrict__ tbl, int ne, int nb, int epb) {
    __shared__ int lcnt[1024];
    const int k = blockIdx.x, t = threadIdx.x;
    for (int b = t; b < nb; b += 256) lcnt[b] = 0;
    __syncthreads();
    const int beg = k * epb, end = min(ne, beg + epb);
    for (int j = beg + t; j < end; j += 256)
        atomicAdd(&lcnt[dst[j] >> BSH], 1);
    __syncthreads();
    for (int b = t; b < nb; b += 256) tbl[b * NBLK + k] = lcnt[b];
}

// ---- 2. hierarchical exclusive scan of tbl[0..sz)
__global__ __launch_bounds__(256) void scan_p1_kernel(const int* __restrict__ tbl,
        int* __restrict__ bsum, int sz) {
    __shared__ int sh[256];
    const int g = blockIdx.x, t = threadIdx.x;
    const int base = g * SCAN_CHUNK + t * 4;
    int s = 0;
    if (base + 3 < sz) {
        int4 v = *(const int4*)(tbl + base);
        s = v.x + v.y + v.z + v.w;
    } else {
        for (int i = 0; i < 4; ++i) if (base + i < sz) s += tbl[base + i];
    }
    sh[t] = s;
    __syncthreads();
    for (int off = 128; off > 0; off >>= 1) {
        if (t < off) sh[t] += sh[t + off];
        __syncthreads();
    }
    if (t == 0) bsum[g] = sh[0];
}

__global__ __launch_bounds__(256) void scan_p2_kernel(int* __restrict__ bsum, int ng) {
    __shared__ int sh[256];
    const int t = threadIdx.x;
    int v = (t < ng) ? bsum[t] : 0;
    sh[t] = v;
    __syncthreads();
    for (int off = 1; off < 256; off <<= 1) {
        int a = sh[t];
        int b = (t >= off) ? sh[t - off] : 0;
        __syncthreads();
        sh[t] = a + b;
        __syncthreads();
    }
    if (t < ng) bsum[t] = sh[t] - v;   // exclusive
}

__global__ __launch_bounds__(256) void scan_p3_kernel(int* __restrict__ tbl,
        const int* __restrict__ bsum, int sz) {
    __shared__ int sh[256];
    const int g = blockIdx.x, t = threadIdx.x;
    const int base = g * SCAN_CHUNK + t * 4;
    int4 v = make_int4(0, 0, 0, 0);
    if (base + 3 < sz) {
        v = *(const int4*)(tbl + base);
    } else {
        if (base + 0 < sz) v.x = tbl[base + 0];
        if (base + 1 < sz) v.y = tbl[base + 1];
        if (base + 2 < sz) v.z = tbl[base + 2];
    }
    int s = v.x + v.y + v.z + v.w;
    sh[t] = s;
    __syncthreads();
    for (int off = 1; off < 256; off <<= 1) {
        int a = sh[t];
        int b = (t >= off) ? sh[t - off] : 0;
        __syncthreads();
        sh[t] = a + b;
        __syncthreads();
    }
    int pre = bsum[g] + sh[t] - s;
    int o0 = pre, o1 = pre + v.x, o2 = o1 + v.y, o3 = o2 + v.z;
    if (base + 3 < sz) {
        *(int4*)(tbl + base) = make_int4(o0, o1, o2, o3);
    } else {
        if (base + 0 < sz) tbl[base + 0] = o0;
        if (base + 1 < sz) tbl[base + 1] = o1;
        if (base + 2 < sz) tbl[base + 2] = o2;
    }
}

// ---- 3. scatter edges into block-private per-bucket subranges (packed)
__global__ __launch_bounds__(256) void bucket_scatter_kernel(
        const int* __restrict__ src, const int* __restrict__ dst,
        const int* __restrict__ tbl, int* __restrict__ pairs,
        int ne, int nb, int epb) {
    __shared__ int cur[1024];
    const int k = blockIdx.x, t = threadIdx.x;
    for (int b = t; b < nb; b += 256) cur[b] = tbl[b * NBLK + k];
    __syncthreads();
    const int beg = k * epb, end = min(ne, beg + epb);
    for (int j = beg + t; j < end; j += 256) {
        int d = dst[j];
        int pos = atomicAdd(&cur[d >> BSH], 1);
        pairs[pos] = (src[j] << BSH) | (d & 63);
    }
}

// ---- 4. per-bucket fine scatter; also writes row_ptr
__global__ __launch_bounds__(256) void fine_scatter_kernel(
        const int* __restrict__ pairs, const int* __restrict__ tbl,
        int* __restrict__ row_ptr, int* __restrict__ eidx,
        int ne, int nb, int n) {
    __shared__ int cnt[64], cur[64];
    const int b = blockIdx.x, t = threadIdx.x;
    const int node0 = b << BSH;
    if (t < 64) cnt[t] = 0;
    __syncthreads();
    const int beg = tbl[b * NBLK];
    const int end = (b == nb - 1) ? ne : tbl[(b + 1) * NBLK];
    for (int j = beg + t; j < end; j += 256) atomicAdd(&cnt[pairs[j] & 63], 1);
    __syncthreads();
    if (t == 0) {
        int run = beg;
        #pragma unroll
        for (int i = 0; i < 64; ++i) { cur[i] = run; run += cnt[i]; }
    }
    __syncthreads();
    if (t < 64 && node0 + t < n) row_ptr[node0 + t] = cur[t];
    if (b == nb - 1 && t == 0) row_ptr[n] = ne;
    __syncthreads();
    for (int j = beg + t; j < end; j += 256) {
        int v = pairs[j];
        int pos = atomicAdd(&cur[v & 63], 1);
        eidx[pos] = v >> BSH;
    }
}

// ------------------------------------------------------------- aggregation
// one 32-lane group per node; each lane owns 4 bf16 dims (8B = uint2)
__global__ __launch_bounds__(256) void aggregate_bf_kernel(
        const uint2* __restrict__ xb, const int* __restrict__ row_ptr,
        const int* __restrict__ eidx, uint2* __restrict__ aggb, int n) {
    int g = (int)((blockIdx.x * blockDim.x + threadIdx.x) >> 5);
    int lane = threadIdx.x & 31;
    if (g >= n) return;
    const int beg = row_ptr[g], end = row_ptr[g + 1];
    float4 acc = make_float4(0.f, 0.f, 0.f, 0.f);
    int e = beg;
    for (; e + 4 <= end; e += 4) {
        int s0 = eidx[e], s1 = eidx[e + 1], s2 = eidx[e + 2], s3 = eidx[e + 3];
        uint2 v0 = xb[(size_t)s0 * 32 + lane];
        uint2 v1 = xb[(size_t)s1 * 32 + lane];
        uint2 v2 = xb[(size_t)s2 * 32 + lane];
        uint2 v3 = xb[(size_t)s3 * 32 + lane];
        acc.x += __uint_as_float(v0.x << 16); acc.y += __uint_as_float(v0.x & 0xffff0000u);
        acc.z += __uint_as_float(v0.y << 16); acc.w += __uint_as_float(v0.y & 0xffff0000u);
        acc.x += __uint_as_float(v1.x << 16); acc.y += __uint_as_float(v1.x & 0xffff0000u);
        acc.z += __uint_as_float(v1.y << 16); acc.w += __uint_as_float(v1.y & 0xffff0000u);
        acc.x += __uint_as_float(v2.x << 16); acc.y += __uint_as_float(v2.x & 0xffff0000u);
        acc.z += __uint_as_float(v2.y << 16); acc.w += __uint_as_float(v2.y & 0xffff0000u);
        acc.x += __uint_as_float(v3.x << 16); acc.y += __uint_as_float(v3.x & 0xffff0000u);
        acc.z += __uint_as_float(v3.y << 16); acc.w += __uint_as_float(v3.y & 0xffff0000u);
    }
    for (; e < end; ++e) {
        int s = eidx[e];
        uint2 v = xb[(size_t)s * 32 + lane];
        acc.x += __uint_as_float(v.x << 16); acc.y += __uint_as_float(v.x & 0xffff0000u);
        acc.z += __uint_as_float(v.y << 16); acc.w += __uint_as_float(v.y & 0xffff0000u);
    }
    uint2 o;
    o.x = (unsigned)f2bf(acc.x) | ((unsigned)f2bf(acc.y) << 16);
    o.y = (unsigned)f2bf(acc.z) | ((unsigned)f2bf(acc.w) << 16);
    aggb[(size_t)g * 32 + lane] = o;
}

// ---------------------------------------------------------- GEMM bf16 MFMA
// out[M,128] = relu(A[M,128] @ W + b), A,out bf16, acc f32.
// 4 waves/block; wave w owns rows [blk*64+w*16, +16), all 8 col-tiles.
__global__ __launch_bounds__(256) void gemm_mfma_kernel(
        const short* __restrict__ A, const short* __restrict__ packw,
        const float* __restrict__ bias, unsigned short* __restrict__ out, int M) {
    const int w = threadIdx.x >> 6, l = threadIdx.x & 63;
    const int m = l & 15, hi = l >> 4;
    const int row0 = blockIdx.x * 64 + w * 16;
    const int arow = row0 + m;
    const bool valid = arow < M;

    short8 afrag[4];
    #pragma unroll
    for (int kk = 0; kk < 4; ++kk) {
        if (valid)
            afrag[kk] = *(const short8*)(A + (size_t)arow * 128 + kk * 32 + hi * 8);
        else
            afrag[kk] = short8{0, 0, 0, 0, 0, 0, 0, 0};
    }

    f32x4 acc[8] = {};
    #pragma unroll
    for (int kk = 0; kk < 4; ++kk) {
        #pragma unroll
        for (int c = 0; c < 8; ++c) {
            short8 bfrag = *(const short8*)(packw + ((size_t)(c * 4 + kk) * 64 + l) * 8);
            acc[c] = __builtin_amdgcn_mfma_f32_16x16x32_bf16(afrag[kk], bfrag, acc[c], 0, 0, 0);
        }
    }

    #pragma unroll
    for (int c = 0; c < 8; ++c) {
        float bcol = bias[c * 16 + m];
        #pragma unroll
        for (int r = 0; r < 4; ++r) {
            int row = row0 + hi * 4 + r;
            if (row < M)
                out[(size_t)row * 128 + c * 16 + m] = f2bf(fmaxf(acc[c][r] + bcol, 0.f));
        }
    }
}

// ---------------------------------------------------------------- heads
// stage 1: 256 blocks x (8 row-lanes x 32 col-groups), uint2 loads, LDS tree
__global__ __launch_bounds__(256) void colsum_part_kernel(
        const uint2* __restrict__ hb, float* __restrict__ part, int n) {
    __shared__ float sh[8][32][4];
    const int t = threadIdx.x;
    const int cg = t & 31, rl = t >> 5;
    float4 acc = make_float4(0.f, 0.f, 0.f, 0.f);
    for (int r = blockIdx.x * 8 + rl; r < n; r += gridDim.x * 8) {
        uint2 v = hb[(size_t)r * 32 + cg];
        acc.x += __uint_as_float(v.x << 16);
        acc.y += __uint_as_float(v.x & 0xffff0000u);
        acc.z += __uint_as_float(v.y << 16);
        acc.w += __uint_as_float(v.y & 0xffff0000u);
    }
    sh[rl][cg][0] = acc.x; sh[rl][cg][1] = acc.y;
    sh[rl][cg][2] = acc.z; sh[rl][cg][3] = acc.w;
    __syncthreads();
    for (int off = 4; off > 0; off >>= 1) {
        if (rl < off) {
            #pragma unroll
            for (int i = 0; i < 4; ++i)
                sh[rl][cg][i] += sh[rl + off][cg][i];
        }
        __syncthreads();
    }
    if (rl == 0) {
        #pragma unroll
        for (int i = 0; i < 4; ++i)
            part[blockIdx.x * 128 + cg * 4 + i] = sh[0][cg][i];
    }
}

__global__ __launch_bounds__(128) void head_final_kernel(
        const float* __restrict__ part, int nparts,
        const float* __restrict__ w_v, const float* __restrict__ b_v,
        const float* __restrict__ w_pd, const float* __restrict__ b_pd,
        float* __restrict__ out, int n_nodes) {
    __shared__ float sv[128], sd[128];
    int d = threadIdx.x;
    float s = 0.f;
    for (int i = 0; i < nparts; ++i) s += part[i * 128 + d];
    float m = s / (float)n_nodes;
    sv[d] = m * w_v[d];
    sd[d] = m * w_pd[d];
    __syncthreads();
    for (int off = 64; off > 0; off >>= 1) {
        if (d < off) { sv[d] += sv[d + off]; sd[d] += sd[d + off]; }
        __syncthreads();
    }
    if (d == 0) {
        out[n_nodes] = sd[0] + b_pd[0];
        out[n_nodes + 1] = sv[0] + b_v[0];
    }
}

__global__ __launch_bounds__(256) void pig_kernel(
        const unsigned short* __restrict__ h, const float* __restrict__ w_pg,
        const float* __restrict__ b_pg, float* __restrict__ out, int n) {
    int g = (int)((blockIdx.x * blockDim.x + threadIdx.x) >> 6);
    int l = threadIdx.x & 63;
    if (g >= n) return;
    float acc = bf2f(h[(size_t)g * 128 + l]) * w_pg[l] +
                bf2f(h[(size_t)g * 128 + 64 + l]) * w_pg[64 + l];
    #pragma unroll
    for (int off = 32; off > 0; off >>= 1) acc += __shfl_xor(acc, off);
    if (l == 0) out[g] = acc + b_pg[0];
}

// ---------------------------------------------------------------- launcher
static inline size_t align_up(size_t v, size_t a) { return (v + a - 1) & ~(a - 1); }

extern "C" void kernel_launch(void* const* d_in, const int* in_sizes, int n_in,
                              void* d_out, int out_size, void* d_ws, size_t ws_size,
                              hipStream_t stream) {
    const float* x    = (const float*)d_in[0];
    const int*   src  = (const int*)d_in[1];
    const int*   dst  = (const int*)d_in[2];
    const float* W0   = (const float*)d_in[3];
    const float* b0   = (const float*)d_in[4];
    const float* W1   = (const float*)d_in[5];
    const float* b1   = (const float*)d_in[6];
    const float* W2   = (const float*)d_in[7];
    const float* b2   = (const float*)d_in[8];
    const float* w_pg = (const float*)d_in[9];
    const float* b_pg = (const float*)d_in[10];
    const float* w_pd = (const float*)d_in[11];
    const float* b_pd = (const float*)d_in[12];
    const float* w_v  = (const float*)d_in[13];
    const float* b_v  = (const float*)d_in[14];
    float* out = (float*)d_out;

    const int NN = in_sizes[0] / HID;          // 50000
    const int NE = in_sizes[1];                // 1600000
    const int NB = (NN + 63) >> BSH;           // coarse buckets
    const int SZ = NB * NBLK;                  // histogram table (~200K ints)
    const int EPB = (NE + NBLK - 1) / NBLK;
    const int NG = (SZ + SCAN_CHUNK - 1) / SCAN_CHUNK;

    // workspace carve-up
    char* w = (char*)d_ws;
    int* tbl      = (int*)w;            w += align_up((size_t)SZ * 4, 256);
    int* bsum     = (int*)w;            w += align_up((size_t)256 * 4, 256);
    int* row_ptr  = (int*)w;            w += align_up((size_t)(NN + 1) * 4, 256);
    int* eidx     = (int*)w;            w += align_up((size_t)NE * 4, 256);
    unsigned short* xb   = (unsigned short*)w; w += align_up((size_t)NN * HID * 2, 256);
    unsigned short* aggb = (unsigned short*)w; w += align_up((size_t)NN * HID * 2, 256);
    unsigned short* hb   = (unsigned short*)w; w += align_up((size_t)NN * HID * 2, 256);
    unsigned short* pw0  = (unsigned short*)w; w += align_up((size_t)16384 * 2, 256);
    unsigned short* pw1  = (unsigned short*)w; w += align_up((size_t)16384 * 2, 256);
    unsigned short* pw2  = (unsigned short*)w; w += align_up((size_t)16384 * 2, 256);
    float* part   = (float*)w;          w += align_up((size_t)CS_BLOCKS * 128 * 4, 256);
    int* pairs    = (int*)aggb;  // alias: pairs (6.4MB) dead before aggb written
    (void)ws_size; (void)n_in; (void)out_size;

    // ---- converts (independent of CSR)
    f32_to_bf16_kernel<<<2048, 256, 0, stream>>>((const float4*)x, (ushort4*)xb, NN * 32);
    pack_w_kernel<<<16, 256, 0, stream>>>(W0, pw0);
    pack_w_kernel<<<16, 256, 0, stream>>>(W1, pw1);
    pack_w_kernel<<<16, 256, 0, stream>>>(W2, pw2);

    // ---- build CSR by dst (reused for all 3 layers)
    bhist_kernel<<<NBLK, 256, 0, stream>>>(dst, tbl, NE, NB, EPB);
    scan_p1_kernel<<<NG, 256, 0, stream>>>(tbl, bsum, SZ);
    scan_p2_kernel<<<1, 256, 0, stream>>>(bsum, NG);
    scan_p3_kernel<<<NG, 256, 0, stream>>>(tbl, bsum, SZ);
    bucket_scatter_kernel<<<NBLK, 256, 0, stream>>>(src, dst, tbl, pairs, NE, NB, EPB);
    fine_scatter_kernel<<<NB, 256, 0, stream>>>(pairs, tbl, row_ptr, eidx, NE, NB, NN);

    const int agg_blocks = (NN * 32 + 255) / 256;
    const int gemm_blocks = (NN + 63) / 64;

    aggregate_bf_kernel<<<agg_blocks, 256, 0, stream>>>((const uint2*)xb, row_ptr, eidx,
                                                        (uint2*)aggb, NN);
    gemm_mfma_kernel<<<gemm_blocks, 256, 0, stream>>>((const short*)aggb, (const short*)pw0,
                                                      b0, hb, NN);
    aggregate_bf_kernel<<<agg_blocks, 256, 0, stream>>>((const uint2*)hb, row_ptr, eidx,
                                                        (uint2*)aggb, NN);
    gemm_mfma_kernel<<<gemm_blocks, 256, 0, stream>>>((const short*)aggb, (const short*)pw1,
                                                      b1, hb, NN);
    aggregate_bf_kernel<<<agg_blocks, 256, 0, stream>>>((const uint2*)hb, row_ptr, eidx,
                                                        (uint2*)aggb, NN);
    gemm_mfma_kernel<<<gemm_blocks, 256, 0, stream>>>((const short*)aggb, (const short*)pw2,
                                                      b2, hb, NN);

    // ---- heads
    colsum_part_kernel<<<CS_BLOCKS, 256, 0, stream>>>((const uint2*)hb, part, NN);
    head_final_kernel<<<1, 128, 0, stream>>>(part, CS_BLOCKS, w_v, b_v, w_pd, b_pd, out, NN);
    pig_kernel<<<(NN * 64 + 255) / 256, 256, 0, stream>>>(hb, w_pg, b_pg, out, NN);
}

// Round 6
// 291.131 us; speedup vs baseline: 3.1367x; 1.1973x over previous
//
#include <hip/hip_runtime.h>
#include <hip/hip_bf16.h>

// GCN actor-critic, bf16 feature pipeline:
//   CSR build (counting sort) -> 3x [bf16 gather-sum -> MFMA bf16 GEMM+ReLU]
//   -> heads. All accumulation in f32; features stored bf16 (RNE).

#define HID 128
#define NBLK 256       // edge-partition blocks
#define BSH 6          // 64 nodes per coarse bucket
#define SCAN_CHUNK 1024
#define CS_BLOCKS 256  // colsum partial blocks

typedef __attribute__((ext_vector_type(8))) short short8;
typedef __attribute__((ext_vector_type(4))) float f32x4;

__device__ __forceinline__ unsigned short f2bf(float f) {
    unsigned int u = __float_as_uint(f);
    unsigned int r = (u + 0x7fffu + ((u >> 16) & 1u)) >> 16;   // RNE
    return (unsigned short)r;
}
__device__ __forceinline__ float bf2f(unsigned short u) {
    return __uint_as_float(((unsigned int)u) << 16);
}

// ---------------------------------------------------------------- converts
__global__ __launch_bounds__(256) void f32_to_bf16_kernel(
        const float4* __restrict__ in, ushort4* __restrict__ out, int n4) {
    for (int i = blockIdx.x * blockDim.x + threadIdx.x; i < n4; i += gridDim.x * blockDim.x) {
        float4 v = in[i];
        ushort4 o;
        o.x = f2bf(v.x); o.y = f2bf(v.y); o.z = f2bf(v.z); o.w = f2bf(v.w);
        out[i] = o;
    }
}

// pack W[128][128] f32 into B-fragment order: packw[((c*4+kk)*64+lane)*8+i] =
// bf16(W[kk*32 + (lane>>4)*8 + i][c*16 + (lane&15)])
__global__ __launch_bounds__(256) void pack_w_kernel(
        const float* __restrict__ W, unsigned short* __restrict__ packw) {
    for (int j = blockIdx.x * blockDim.x + threadIdx.x; j < 16384; j += gridDim.x * blockDim.x) {
        int i = j & 7, lane = (j >> 3) & 63, kk = (j >> 9) & 3, c = (j >> 11) & 7;
        int k = kk * 32 + (lane >> 4) * 8 + i;
        int col = c * 16 + (lane & 15);
        packw[j] = f2bf(W[k * 128 + col]);
    }
}

// ---- 1. coarse histogram: tbl[b*NBLK + k] = #edges of block k in bucket b
__global__ __launch_bounds__(256) void bhist_kernel(const int* __restrict__ dst,
        int* __restrict__ tbl, int ne, int nb, int epb) {
    __shared__ int lcnt[1024];
    const int k = blockIdx.x, t = threadIdx.x;
    for (int b = t; b < nb; b += 256) lcnt[b] = 0;
    __syncthreads();
    const int beg = k * epb, end = min(ne, beg + epb);
    for (int j = beg + t; j < end; j += 256)
        atomicAdd(&lcnt[dst[j] >> BSH], 1);
    __syncthreads();
    for (int b = t; b < nb; b += 256) tbl[b * NBLK + k] = lcnt[b];
}

// ---- 2. hierarchical exclusive scan of tbl[0..sz)
__global__ __launch_bounds__(256) void scan_p1_kernel(const int* __restrict__ tbl,
        int* __restrict__ bsum, int sz) {
    __shared__ int sh[256];
    const int g = blockIdx.x, t = threadIdx.x;
    const int base = g * SCAN_CHUNK + t * 4;
    int s = 0;
    if (base + 3 < sz) {
        int4 v = *(const int4*)(tbl + base);
        s = v.x + v.y + v.z + v.w;
    } else {
        for (int i = 0; i < 4; ++i) if (base + i < sz) s += tbl[base + i];
    }
    sh[t] = s;
    __syncthreads();
    for (int off = 128; off > 0; off >>= 1) {
        if (t < off) sh[t] += sh[t + off];
        __syncthreads();
    }
    if (t == 0) bsum[g] = sh[0];
}

__global__ __launch_bounds__(256) void scan_p2_kernel(int* __restrict__ bsum, int ng) {
    __shared__ int sh[256];
    const int t = threadIdx.x;
    int v = (t < ng) ? bsum[t] : 0;
    sh[t] = v;
    __syncthreads();
    for (int off = 1; off < 256; off <<= 1) {
        int a = sh[t];
        int b = (t >= off) ? sh[t - off] : 0;
        __syncthreads();
        sh[t] = a + b;
        __syncthreads();
    }
    if (t < ng) bsum[t] = sh[t] - v;   // exclusive
}

__global__ __launch_bounds__(256) void scan_p3_kernel(int* __restrict__ tbl,
        const int* __restrict__ bsum, int sz) {
    __shared__ int sh[256];
    const int g = blockIdx.x, t = threadIdx.x;
    const int base = g * SCAN_CHUNK + t * 4;
    int4 v = make_int4(0, 0, 0, 0);
    if (base + 3 < sz) {
        v = *(const int4*)(tbl + base);
    } else {
        if (base + 0 < sz) v.x = tbl[base + 0];
        if (base + 1 < sz) v.y = tbl[base + 1];
        if (base + 2 < sz) v.z = tbl[base + 2];
    }
    int s = v.x + v.y + v.z + v.w;
    sh[t] = s;
    __syncthreads();
    for (int off = 1; off < 256; off <<= 1) {
        int a = sh[t];
        int b = (t >= off) ? sh[t - off] : 0;
        __syncthreads();
        sh[t] = a + b;
        __syncthreads();
    }
    int pre = bsum[g] + sh[t] - s;
    int o0 = pre, o1 = pre + v.x, o2 = o1 + v.y, o3 = o2 + v.z;
    if (base + 3 < sz) {
        *(int4*)(tbl + base) = make_int4(o0, o1, o2, o3);
    } else {
        if (base + 0 < sz) tbl[base + 0] = o0;
        if (base + 1 < sz) tbl[base + 1] = o1;
        if (base + 2 < sz) tbl[base + 2] = o2;
    }
}

// ---- 3. scatter edges into block-private per-bucket subranges (packed)
__global__ __launch_bounds__(256) void bucket_scatter_kernel(
        const int* __restrict__ src, const int* __restrict__ dst,
        const int* __restrict__ tbl, int* __restrict__ pairs,
        int ne, int nb, int epb) {
    __shared__ int cur[1024];
    const int k = blockIdx.x, t = threadIdx.x;
    for (int b = t; b < nb; b += 256) cur[b] = tbl[b * NBLK + k];
    __syncthreads();
    const int beg = k * epb, end = min(ne, beg + epb);
    for (int j = beg + t; j < end; j += 256) {
        int d = dst[j];
        int pos = atomicAdd(&cur[d >> BSH], 1);
        pairs[pos] = (src[j] << BSH) | (d & 63);
    }
}

// ---- 4. per-bucket fine scatter; also writes row_ptr
__global__ __launch_bounds__(256) void fine_scatter_kernel(
        const int* __restrict__ pairs, const int* __restrict__ tbl,
        int* __restrict__ row_ptr, int* __restrict__ eidx,
        int ne, int nb, int n) {
    __shared__ int cnt[64], cur[64];
    const int b = blockIdx.x, t = threadIdx.x;
    const int node0 = b << BSH;
    if (t < 64) cnt[t] = 0;
    __syncthreads();
    const int beg = tbl[b * NBLK];
    const int end = (b == nb - 1) ? ne : tbl[(b + 1) * NBLK];
    for (int j = beg + t; j < end; j += 256) atomicAdd(&cnt[pairs[j] & 63], 1);
    __syncthreads();
    if (t == 0) {
        int run = beg;
        #pragma unroll
        for (int i = 0; i < 64; ++i) { cur[i] = run; run += cnt[i]; }
    }
    __syncthreads();
    if (t < 64 && node0 + t < n) row_ptr[node0 + t] = cur[t];
    if (b == nb - 1 && t == 0) row_ptr[n] = ne;
    __syncthreads();
    for (int j = beg + t; j < end; j += 256) {
        int v = pairs[j];
        int pos = atomicAdd(&cur[v & 63], 1);
        eidx[pos] = v >> BSH;
    }
}

// ------------------------------------------------------------- aggregation
// one 32-lane group per node; each lane owns 4 bf16 dims (8B = uint2)
__global__ __launch_bounds__(256) void aggregate_bf_kernel(
        const uint2* __restrict__ xb, const int* __restrict__ row_ptr,
        const int* __restrict__ eidx, uint2* __restrict__ aggb, int n) {
    int g = (int)((blockIdx.x * blockDim.x + threadIdx.x) >> 5);
    int lane = threadIdx.x & 31;
    if (g >= n) return;
    const int beg = row_ptr[g], end = row_ptr[g + 1];
    float4 acc = make_float4(0.f, 0.f, 0.f, 0.f);
    int e = beg;
    for (; e + 4 <= end; e += 4) {
        int s0 = eidx[e], s1 = eidx[e + 1], s2 = eidx[e + 2], s3 = eidx[e + 3];
        uint2 v0 = xb[(size_t)s0 * 32 + lane];
        uint2 v1 = xb[(size_t)s1 * 32 + lane];
        uint2 v2 = xb[(size_t)s2 * 32 + lane];
        uint2 v3 = xb[(size_t)s3 * 32 + lane];
        acc.x += __uint_as_float(v0.x << 16); acc.y += __uint_as_float(v0.x & 0xffff0000u);
        acc.z += __uint_as_float(v0.y << 16); acc.w += __uint_as_float(v0.y & 0xffff0000u);
        acc.x += __uint_as_float(v1.x << 16); acc.y += __uint_as_float(v1.x & 0xffff0000u);
        acc.z += __uint_as_float(v1.y << 16); acc.w += __uint_as_float(v1.y & 0xffff0000u);
        acc.x += __uint_as_float(v2.x << 16); acc.y += __uint_as_float(v2.x & 0xffff0000u);
        acc.z += __uint_as_float(v2.y << 16); acc.w += __uint_as_float(v2.y & 0xffff0000u);
        acc.x += __uint_as_float(v3.x << 16); acc.y += __uint_as_float(v3.x & 0xffff0000u);
        acc.z += __uint_as_float(v3.y << 16); acc.w += __uint_as_float(v3.y & 0xffff0000u);
    }
    for (; e < end; ++e) {
        int s = eidx[e];
        uint2 v = xb[(size_t)s * 32 + lane];
        acc.x += __uint_as_float(v.x << 16); acc.y += __uint_as_float(v.x & 0xffff0000u);
        acc.z += __uint_as_float(v.y << 16); acc.w += __uint_as_float(v.y & 0xffff0000u);
    }
    uint2 o;
    o.x = (unsigned)f2bf(acc.x) | ((unsigned)f2bf(acc.y) << 16);
    o.y = (unsigned)f2bf(acc.z) | ((unsigned)f2bf(acc.w) << 16);
    aggb[(size_t)g * 32 + lane] = o;
}

// ---------------------------------------------------------- GEMM bf16 MFMA
// out[M,128] = relu(A[M,128] @ W + b), A,out bf16, acc f32.
// 4 waves/block; wave w owns rows [blk*64+w*16, +16), all 8 col-tiles.
__global__ __launch_bounds__(256) void gemm_mfma_kernel(
        const short* __restrict__ A, const short* __restrict__ packw,
        const float* __restrict__ bias, unsigned short* __restrict__ out, int M) {
    const int w = threadIdx.x >> 6, l = threadIdx.x & 63;
    const int m = l & 15, hi = l >> 4;
    const int row0 = blockIdx.x * 64 + w * 16;
    const int arow = row0 + m;
    const bool valid = arow < M;

    short8 afrag[4];
    #pragma unroll
    for (int kk = 0; kk < 4; ++kk) {
        if (valid)
            afrag[kk] = *(const short8*)(A + (size_t)arow * 128 + kk * 32 + hi * 8);
        else
            afrag[kk] = short8{0, 0, 0, 0, 0, 0, 0, 0};
    }

    f32x4 acc[8] = {};
    #pragma unroll
    for (int kk = 0; kk < 4; ++kk) {
        #pragma unroll
        for (int c = 0; c < 8; ++c) {
            short8 bfrag = *(const short8*)(packw + ((size_t)(c * 4 + kk) * 64 + l) * 8);
            acc[c] = __builtin_amdgcn_mfma_f32_16x16x32_bf16(afrag[kk], bfrag, acc[c], 0, 0, 0);
        }
    }

    #pragma unroll
    for (int c = 0; c < 8; ++c) {
        float bcol = bias[c * 16 + m];
        #pragma unroll
        for (int r = 0; r < 4; ++r) {
            int row = row0 + hi * 4 + r;
            if (row < M)
                out[(size_t)row * 128 + c * 16 + m] = f2bf(fmaxf(acc[c][r] + bcol, 0.f));
        }
    }
}

// ---------------------------------------------------------------- heads
// stage 1: 256 blocks x (8 row-lanes x 32 col-groups), uint2 loads, LDS tree
__global__ __launch_bounds__(256) void colsum_part_kernel(
        const uint2* __restrict__ hb, float* __restrict__ part, int n) {
    __shared__ float sh[8][32][4];
    const int t = threadIdx.x;
    const int cg = t & 31, rl = t >> 5;
    float4 acc = make_float4(0.f, 0.f, 0.f, 0.f);
    for (int r = blockIdx.x * 8 + rl; r < n; r += gridDim.x * 8) {
        uint2 v = hb[(size_t)r * 32 + cg];
        acc.x += __uint_as_float(v.x << 16);
        acc.y += __uint_as_float(v.x & 0xffff0000u);
        acc.z += __uint_as_float(v.y << 16);
        acc.w += __uint_as_float(v.y & 0xffff0000u);
    }
    sh[rl][cg][0] = acc.x; sh[rl][cg][1] = acc.y;
    sh[rl][cg][2] = acc.z; sh[rl][cg][3] = acc.w;
    __syncthreads();
    for (int off = 4; off > 0; off >>= 1) {
        if (rl < off) {
            #pragma unroll
            for (int i = 0; i < 4; ++i)
                sh[rl][cg][i] += sh[rl + off][cg][i];
        }
        __syncthreads();
    }
    if (rl == 0) {
        #pragma unroll
        for (int i = 0; i < 4; ++i)
            part[blockIdx.x * 128 + cg * 4 + i] = sh[0][cg][i];
    }
}

// stage 2: one 1024-thread block; 32 partial-groups x 32 float4 col-groups
__global__ __launch_bounds__(1024) void head_final_kernel(
        const float* __restrict__ part, int nparts,
        const float* __restrict__ w_v, const float* __restrict__ b_v,
        const float* __restrict__ w_pd, const float* __restrict__ b_pd,
        float* __restrict__ out, int n_nodes) {
    __shared__ float sh[32][128];
    __shared__ float sv[128], sd[128];
    const int t = threadIdx.x;
    const int d4 = t & 31, pg = t >> 5;
    float4 acc = make_float4(0.f, 0.f, 0.f, 0.f);
    for (int i = pg; i < nparts; i += 32) {
        float4 v = *(const float4*)(part + (size_t)i * 128 + d4 * 4);
        acc.x += v.x; acc.y += v.y; acc.z += v.z; acc.w += v.w;
    }
    *(float4*)&sh[pg][d4 * 4] = acc;
    __syncthreads();
    for (int off = 16; off > 0; off >>= 1) {
        if (pg < off) {
            float4 a = *(float4*)&sh[pg][d4 * 4];
            float4 b = *(float4*)&sh[pg + off][d4 * 4];
            a.x += b.x; a.y += b.y; a.z += b.z; a.w += b.w;
            *(float4*)&sh[pg][d4 * 4] = a;
        }
        __syncthreads();
    }
    if (t < 128) {
        float m = sh[0][t] / (float)n_nodes;
        sv[t] = m * w_v[t];
        sd[t] = m * w_pd[t];
    }
    __syncthreads();
    for (int off = 64; off > 0; off >>= 1) {
        if (t < off) { sv[t] += sv[t + off]; sd[t] += sd[t + off]; }
        __syncthreads();
    }
    if (t == 0) {
        out[n_nodes] = sd[0] + b_pd[0];
        out[n_nodes + 1] = sv[0] + b_v[0];
    }
}

__global__ __launch_bounds__(256) void pig_kernel(
        const unsigned short* __restrict__ h, const float* __restrict__ w_pg,
        const float* __restrict__ b_pg, float* __restrict__ out, int n) {
    int g = (int)((blockIdx.x * blockDim.x + threadIdx.x) >> 6);
    int l = threadIdx.x & 63;
    if (g >= n) return;
    float acc = bf2f(h[(size_t)g * 128 + l]) * w_pg[l] +
                bf2f(h[(size_t)g * 128 + 64 + l]) * w_pg[64 + l];
    #pragma unroll
    for (int off = 32; off > 0; off >>= 1) acc += __shfl_xor(acc, off);
    if (l == 0) out[g] = acc + b_pg[0];
}

// ---------------------------------------------------------------- launcher
static inline size_t align_up(size_t v, size_t a) { return (v + a - 1) & ~(a - 1); }

extern "C" void kernel_launch(void* const* d_in, const int* in_sizes, int n_in,
                              void* d_out, int out_size, void* d_ws, size_t ws_size,
                              hipStream_t stream) {
    const float* x    = (const float*)d_in[0];
    const int*   src  = (const int*)d_in[1];
    const int*   dst  = (const int*)d_in[2];
    const float* W0   = (const float*)d_in[3];
    const float* b0   = (const float*)d_in[4];
    const float* W1   = (const float*)d_in[5];
    const float* b1   = (const float*)d_in[6];
    const float* W2   = (const float*)d_in[7];
    const float* b2   = (const float*)d_in[8];
    const float* w_pg = (const float*)d_in[9];
    const float* b_pg = (const float*)d_in[10];
    const float* w_pd = (const float*)d_in[11];
    const float* b_pd = (const float*)d_in[12];
    const float* w_v  = (const float*)d_in[13];
    const float* b_v  = (const float*)d_in[14];
    float* out = (float*)d_out;

    const int NN = in_sizes[0] / HID;          // 50000
    const int NE = in_sizes[1];                // 1600000
    const int NB = (NN + 63) >> BSH;           // coarse buckets
    const int SZ = NB * NBLK;                  // histogram table (~200K ints)
    const int EPB = (NE + NBLK - 1) / NBLK;
    const int NG = (SZ + SCAN_CHUNK - 1) / SCAN_CHUNK;

    // workspace carve-up
    char* w = (char*)d_ws;
    int* tbl      = (int*)w;            w += align_up((size_t)SZ * 4, 256);
    int* bsum     = (int*)w;            w += align_up((size_t)256 * 4, 256);
    int* row_ptr  = (int*)w;            w += align_up((size_t)(NN + 1) * 4, 256);
    int* eidx     = (int*)w;            w += align_up((size_t)NE * 4, 256);
    unsigned short* xb   = (unsigned short*)w; w += align_up((size_t)NN * HID * 2, 256);
    unsigned short* aggb = (unsigned short*)w; w += align_up((size_t)NN * HID * 2, 256);
    unsigned short* hb   = (unsigned short*)w; w += align_up((size_t)NN * HID * 2, 256);
    unsigned short* pw0  = (unsigned short*)w; w += align_up((size_t)16384 * 2, 256);
    unsigned short* pw1  = (unsigned short*)w; w += align_up((size_t)16384 * 2, 256);
    unsigned short* pw2  = (unsigned short*)w; w += align_up((size_t)16384 * 2, 256);
    float* part   = (float*)w;          w += align_up((size_t)CS_BLOCKS * 128 * 4, 256);
    int* pairs    = (int*)aggb;  // alias: pairs (6.4MB) dead before aggb written
    (void)ws_size; (void)n_in; (void)out_size;

    // ---- converts (independent of CSR)
    f32_to_bf16_kernel<<<2048, 256, 0, stream>>>((const float4*)x, (ushort4*)xb, NN * 32);
    pack_w_kernel<<<16, 256, 0, stream>>>(W0, pw0);
    pack_w_kernel<<<16, 256, 0, stream>>>(W1, pw1);
    pack_w_kernel<<<16, 256, 0, stream>>>(W2, pw2);

    // ---- build CSR by dst (reused for all 3 layers)
    bhist_kernel<<<NBLK, 256, 0, stream>>>(dst, tbl, NE, NB, EPB);
    scan_p1_kernel<<<NG, 256, 0, stream>>>(tbl, bsum, SZ);
    scan_p2_kernel<<<1, 256, 0, stream>>>(bsum, NG);
    scan_p3_kernel<<<NG, 256, 0, stream>>>(tbl, bsum, SZ);
    bucket_scatter_kernel<<<NBLK, 256, 0, stream>>>(src, dst, tbl, pairs, NE, NB, EPB);
    fine_scatter_kernel<<<NB, 256, 0, stream>>>(pairs, tbl, row_ptr, eidx, NE, NB, NN);

    const int agg_blocks = (NN * 32 + 255) / 256;
    const int gemm_blocks = (NN + 63) / 64;

    aggregate_bf_kernel<<<agg_blocks, 256, 0, stream>>>((const uint2*)xb, row_ptr, eidx,
                                                        (uint2*)aggb, NN);
    gemm_mfma_kernel<<<gemm_blocks, 256, 0, stream>>>((const short*)aggb, (const short*)pw0,
                                                      b0, hb, NN);
    aggregate_bf_kernel<<<agg_blocks, 256, 0, stream>>>((const uint2*)hb, row_ptr, eidx,
                                                        (uint2*)aggb, NN);
    gemm_mfma_kernel<<<gemm_blocks, 256, 0, stream>>>((const short*)aggb, (const short*)pw1,
                                                      b1, hb, NN);
    aggregate_bf_kernel<<<agg_blocks, 256, 0, stream>>>((const uint2*)hb, row_ptr, eidx,
                                                        (uint2*)aggb, NN);
    gemm_mfma_kernel<<<gemm_blocks, 256, 0, stream>>>((const short*)aggb, (const short*)pw2,
                                                      b2, hb, NN);

    // ---- heads
    colsum_part_kernel<<<CS_BLOCKS, 256, 0, stream>>>((const uint2*)hb, part, NN);
    head_final_kernel<<<1, 1024, 0, stream>>>(part, CS_BLOCKS, w_v, b_v, w_pd, b_pd, out, NN);
    pig_kernel<<<(NN * 64 + 255) / 256, 256, 0, stream>>>(hb, w_pg, b_pg, out, NN);
}